// Round 1
// baseline (1529.003 us; speedup 1.0000x reference)
//
#include <hip/hip_runtime.h>
#include <hip/hip_bf16.h>
#include <math.h>

// Problem constants (also derived from in_sizes in kernel_launch)
#define D_EMB 512
#define HEADS 8
#define DK 32
#define DV 32
#define FKQV (HEADS * DK)   // 256

// ---------------------------------------------------------------------------
// CSR build kernels
// ---------------------------------------------------------------------------
__global__ void count_deg_kernel(const int* __restrict__ recv, int* __restrict__ deg, int M) {
    int e = blockIdx.x * blockDim.x + threadIdx.x;
    if (e < M) atomicAdd(&deg[recv[e]], 1);
}

// Exclusive prefix sum of deg[0..n) -> rowptr[0..n], single block of 1024.
__global__ __launch_bounds__(1024) void scan_kernel(const int* __restrict__ deg,
                                                    int* __restrict__ rowptr, int n) {
    __shared__ int buf[1024];
    __shared__ int carry_s;
    if (threadIdx.x == 0) carry_s = 0;
    __syncthreads();
    for (int base = 0; base < n; base += 1024) {
        int i = base + threadIdx.x;
        int v = (i < n) ? deg[i] : 0;
        buf[threadIdx.x] = v;
        __syncthreads();
        for (int off = 1; off < 1024; off <<= 1) {
            int t = (threadIdx.x >= off) ? buf[threadIdx.x - off] : 0;
            __syncthreads();
            buf[threadIdx.x] += t;
            __syncthreads();
        }
        if (i < n) rowptr[i + 1] = carry_s + buf[threadIdx.x];  // inclusive -> rowptr[i+1]
        __syncthreads();
        if (threadIdx.x == 1023) carry_s += buf[1023];
        __syncthreads();
    }
    if (threadIdx.x == 0) rowptr[0] = 0;
}

__global__ void scatter_kernel(const int* __restrict__ recv, const int* __restrict__ send,
                               const int* __restrict__ rowptr, int* __restrict__ cursor,
                               int* __restrict__ ssend, int M) {
    int e = blockIdx.x * blockDim.x + threadIdx.x;
    if (e < M) {
        int r = recv[e];
        int pos = atomicAdd(&cursor[r], 1);
        ssend[rowptr[r] + pos] = send[e];
    }
}

// ---------------------------------------------------------------------------
// Tiled fp32 GEMM: C[M,F] = op(A[M,K] @ W[K,F] + bias) (+ resid)
// Tile 128x128, K-tile 16, 256 threads, 8x8 micro-tile per thread.
// op order matches reference: relu first, then residual add.
// ---------------------------------------------------------------------------
template<bool RELU, bool RESID>
__global__ __launch_bounds__(256) void gemm_kernel(
    const float* __restrict__ A, const float* __restrict__ W,
    const float* __restrict__ bias, const float* __restrict__ resid,
    float* __restrict__ C, int M, int K, int F)
{
    __shared__ float As[16][128];  // transposed A tile: As[k][row]
    __shared__ float Ws[16][128];  // Ws[k][col]

    const int tid = threadIdx.x;
    const int tx = tid & 15;       // 0..15 -> 8 output cols each
    const int ty = tid >> 4;       // 0..15 -> 8 output rows each
    const int brow = blockIdx.y * 128;
    const int bcol = blockIdx.x * 128;

    // A-tile load mapping: 128 rows x 16 cols, 8 floats (2x float4) per thread
    const int ar = tid >> 1;         // 0..127
    const int ac = (tid & 1) * 8;    // 0 or 8
    // W-tile load mapping: 16 rows x 128 cols
    const int wr = tid >> 4;         // 0..15
    const int wc = (tid & 15) * 8;   // 0..120

    float acc[8][8];
#pragma unroll
    for (int i = 0; i < 8; i++)
#pragma unroll
        for (int j = 0; j < 8; j++) acc[i][j] = 0.0f;

    for (int k0 = 0; k0 < K; k0 += 16) {
        float4 a0 = make_float4(0, 0, 0, 0), a1 = make_float4(0, 0, 0, 0);
        const int grow = brow + ar;
        if (grow < M) {
            const float* ap = A + (size_t)grow * K + k0 + ac;
            a0 = *(const float4*)ap;
            a1 = *(const float4*)(ap + 4);
        }
        const float* wp = W + (size_t)(k0 + wr) * F + bcol + wc;
        const float4 w0 = *(const float4*)wp;
        const float4 w1 = *(const float4*)(wp + 4);

        __syncthreads();  // previous tile's compute done reading LDS
        As[ac + 0][ar] = a0.x; As[ac + 1][ar] = a0.y;
        As[ac + 2][ar] = a0.z; As[ac + 3][ar] = a0.w;
        As[ac + 4][ar] = a1.x; As[ac + 5][ar] = a1.y;
        As[ac + 6][ar] = a1.z; As[ac + 7][ar] = a1.w;
        *(float4*)&Ws[wr][wc]     = w0;
        *(float4*)&Ws[wr][wc + 4] = w1;
        __syncthreads();

#pragma unroll
        for (int k = 0; k < 16; k++) {
            const float4 av0 = *(const float4*)&As[k][ty * 8];
            const float4 av1 = *(const float4*)&As[k][ty * 8 + 4];
            const float4 wv0 = *(const float4*)&Ws[k][tx * 8];
            const float4 wv1 = *(const float4*)&Ws[k][tx * 8 + 4];
            const float a[8] = {av0.x, av0.y, av0.z, av0.w, av1.x, av1.y, av1.z, av1.w};
            const float w[8] = {wv0.x, wv0.y, wv0.z, wv0.w, wv1.x, wv1.y, wv1.z, wv1.w};
#pragma unroll
            for (int i = 0; i < 8; i++)
#pragma unroll
                for (int j = 0; j < 8; j++) acc[i][j] = fmaf(a[i], w[j], acc[i][j]);
        }
    }

    // epilogue
    float bj[8];
#pragma unroll
    for (int j = 0; j < 8; j++) bj[j] = bias[bcol + tx * 8 + j];

#pragma unroll
    for (int i = 0; i < 8; i++) {
        const int row = brow + ty * 8 + i;
        if (row >= M) continue;
        float v[8];
#pragma unroll
        for (int j = 0; j < 8; j++) {
            float t = acc[i][j] + bj[j];
            if (RELU) t = fmaxf(t, 0.0f);
            v[j] = t;
        }
        if (RESID) {
            const float* rp = resid + (size_t)row * F + bcol + tx * 8;
#pragma unroll
            for (int j = 0; j < 8; j++) v[j] += rp[j];
        }
        float* cp = C + (size_t)row * F + bcol + tx * 8;
        *(float4*)cp       = make_float4(v[0], v[1], v[2], v[3]);
        *(float4*)(cp + 4) = make_float4(v[4], v[5], v[6], v[7]);
    }
}

// ---------------------------------------------------------------------------
// Attention gather: one 32-lane group per (receiver, head).
// agg[r, h*32+d] = relu( (sum_e att_e * V[s_e,h,d]) / (sum_e att_e) )
// ---------------------------------------------------------------------------
__global__ __launch_bounds__(256) void attn_kernel(
    const float* __restrict__ Q, const float* __restrict__ Kb, const float* __restrict__ V,
    const int* __restrict__ rowptr, const int* __restrict__ ssend,
    float* __restrict__ agg, int N)
{
    const int grp = threadIdx.x >> 5;          // 0..7
    const int lane = threadIdx.x & 31;         // 0..31 = d
    const int p = blockIdx.x * 8 + grp;        // (node, head) pair id
    if (p >= N * HEADS) return;
    const int r = p >> 3;
    const int h = p & 7;

    const float qd = Q[(size_t)r * FKQV + h * DK + lane];
    const float scale = 0.17677669529663687f;  // 1/sqrt(32)

    float accV = 0.0f;
    float denom = 0.0f;
    const int beg = rowptr[r], end = rowptr[r + 1];
    for (int e = beg; e < end; e++) {
        const int s = ssend[e];
        const size_t base = (size_t)s * FKQV + h * DK;
        float t = qd * Kb[base + lane];
        // reduce across the 32-lane group (stays within half-wave)
        t += __shfl_xor(t, 1);
        t += __shfl_xor(t, 2);
        t += __shfl_xor(t, 4);
        t += __shfl_xor(t, 8);
        t += __shfl_xor(t, 16);
        const float att = expf(t * scale);
        denom += att;
        accV = fmaf(att, V[base + lane], accV);
    }
    float o = (denom > 0.0f) ? (accV / denom) : 0.0f;
    o = fmaxf(o, 0.0f);
    agg[(size_t)r * FKQV + h * DK + lane] = o;
}

// ---------------------------------------------------------------------------
extern "C" void kernel_launch(void* const* d_in, const int* in_sizes, int n_in,
                              void* d_out, int out_size, void* d_ws, size_t ws_size,
                              hipStream_t stream) {
    const float* x  = (const float*)d_in[0];
    const int* eidx = (const int*)d_in[1];
    const float* Wk = (const float*)d_in[2];
    const float* bk = (const float*)d_in[3];
    const float* Wq = (const float*)d_in[4];
    const float* bq = (const float*)d_in[5];
    const float* Wv = (const float*)d_in[6];
    const float* bv = (const float*)d_in[7];
    const float* Wa = (const float*)d_in[8];
    const float* ba = (const float*)d_in[9];
    const float* Wf = (const float*)d_in[10];
    const float* bf = (const float*)d_in[11];
    float* out = (float*)d_out;

    const int N = in_sizes[0] / D_EMB;    // 50000
    const int M = in_sizes[1] / 2;        // 400000
    const int* recv = eidx;
    const int* send = eidx + M;

    // workspace layout (floats then ints)
    float* ws_f = (float*)d_ws;
    float* Kb  = ws_f;                 // N*256
    float* Qb  = Kb + (size_t)N * FKQV;
    float* Vb  = Qb + (size_t)N * FKQV;
    float* agg = Vb + (size_t)N * FKQV;
    float* h1  = Kb;                   // alias K+Q region: N*512 (K,Q dead by then)
    int* rowptr = (int*)(agg + (size_t)N * FKQV);
    int* cursor = rowptr + (N + 1);
    int* ssend  = cursor + N;

    // ---- CSR build ----
    hipMemsetAsync(cursor, 0, (size_t)N * sizeof(int), stream);
    count_deg_kernel<<<(M + 255) / 256, 256, 0, stream>>>(recv, cursor, M);
    scan_kernel<<<1, 1024, 0, stream>>>(cursor, rowptr, N);
    hipMemsetAsync(cursor, 0, (size_t)N * sizeof(int), stream);
    scatter_kernel<<<(M + 255) / 256, 256, 0, stream>>>(recv, send, rowptr, cursor, ssend, M);

    // ---- K, Q, V projections ----
    {
        dim3 g(FKQV / 128, (N + 127) / 128);
        gemm_kernel<false, false><<<g, 256, 0, stream>>>(x, Wk, bk, nullptr, Kb, N, D_EMB, FKQV);
        gemm_kernel<false, false><<<g, 256, 0, stream>>>(x, Wq, bq, nullptr, Qb, N, D_EMB, FKQV);
        gemm_kernel<false, false><<<g, 256, 0, stream>>>(x, Wv, bv, nullptr, Vb, N, D_EMB, FKQV);
    }

    // ---- attention gather (fused normalize + relu) ----
    attn_kernel<<<(N * HEADS + 7) / 8, 256, 0, stream>>>(Qb, Kb, Vb, rowptr, ssend, agg, N);

    // ---- h1 = relu(agg @ Wa + ba) ----
    {
        dim3 g(D_EMB / 128, (N + 127) / 128);
        gemm_kernel<true, false><<<g, 256, 0, stream>>>(agg, Wa, ba, nullptr, h1, N, FKQV, D_EMB);
    }

    // ---- out = x + relu(h1 @ Wf + bf) ----
    {
        dim3 g(D_EMB / 128, (N + 127) / 128);
        gemm_kernel<true, true><<<g, 256, 0, stream>>>(h1, Wf, bf, x, out, N, D_EMB, D_EMB);
    }
}

// Round 2
// 857.065 us; speedup vs baseline: 1.7840x; 1.7840x over previous
//
#include <hip/hip_runtime.h>
#include <hip/hip_bf16.h>
#include <math.h>

#define D_EMB 512
#define HEADS 8
#define DK 32
#define FKQV 768   // K|Q|V combined output width

typedef __attribute__((ext_vector_type(8))) short bf16x8v;
typedef __attribute__((ext_vector_type(4))) float f32x4;

__device__ __forceinline__ unsigned short f2bf(float f) {
    unsigned int u = __float_as_uint(f);
    u += 0x7FFFu + ((u >> 16) & 1u);       // round-to-nearest-even
    return (unsigned short)(u >> 16);
}
__device__ __forceinline__ float bf2f(unsigned short h) {
    return __uint_as_float(((unsigned int)h) << 16);
}

__device__ __forceinline__ void gld_lds16(const void* g, void* l) {
    __builtin_amdgcn_global_load_lds(
        (const __attribute__((address_space(1))) unsigned int*)g,
        (__attribute__((address_space(3))) unsigned int*)l, 16, 0, 0);
}

// ---------------------------------------------------------------------------
// CSR build
// ---------------------------------------------------------------------------
__global__ void count_deg_kernel(const int* __restrict__ recv, int* __restrict__ deg, int M) {
    int e = blockIdx.x * blockDim.x + threadIdx.x;
    if (e < M) atomicAdd(&deg[recv[e]], 1);
}

__global__ __launch_bounds__(1024) void scan_kernel(const int* __restrict__ deg,
                                                    int* __restrict__ rowptr, int n) {
    __shared__ int buf[1024];
    __shared__ int carry_s;
    if (threadIdx.x == 0) carry_s = 0;
    __syncthreads();
    for (int base = 0; base < n; base += 1024) {
        int i = base + threadIdx.x;
        int v = (i < n) ? deg[i] : 0;
        buf[threadIdx.x] = v;
        __syncthreads();
        for (int off = 1; off < 1024; off <<= 1) {
            int t = (threadIdx.x >= off) ? buf[threadIdx.x - off] : 0;
            __syncthreads();
            buf[threadIdx.x] += t;
            __syncthreads();
        }
        if (i < n) rowptr[i + 1] = carry_s + buf[threadIdx.x];
        __syncthreads();
        if (threadIdx.x == 1023) carry_s += buf[1023];
        __syncthreads();
    }
    if (threadIdx.x == 0) rowptr[0] = 0;
}

__global__ void scatter_kernel(const int* __restrict__ recv, const int* __restrict__ send,
                               const int* __restrict__ rowptr, int* __restrict__ cursor,
                               int* __restrict__ ssend, int M) {
    int e = blockIdx.x * blockDim.x + threadIdx.x;
    if (e < M) {
        int r = recv[e];
        int pos = atomicAdd(&cursor[r], 1);
        ssend[rowptr[r] + pos] = send[e];
    }
}

// ---------------------------------------------------------------------------
// x (fp32) -> x_hi, x_lo (bf16 split), 8 floats per thread
// ---------------------------------------------------------------------------
__global__ void split_x_kernel(const float* __restrict__ x, unsigned short* __restrict__ xh,
                               unsigned short* __restrict__ xl, int n8) {
    int i = blockIdx.x * blockDim.x + threadIdx.x;
    if (i >= n8) return;
    const float4 a = ((const float4*)x)[2 * i];
    const float4 b = ((const float4*)x)[2 * i + 1];
    float v[8] = {a.x, a.y, a.z, a.w, b.x, b.y, b.z, b.w};
    unsigned int H[4], L[4];
#pragma unroll
    for (int j = 0; j < 4; j++) {
        unsigned short h0 = f2bf(v[2 * j]), h1 = f2bf(v[2 * j + 1]);
        unsigned short l0 = f2bf(v[2 * j] - bf2f(h0)), l1 = f2bf(v[2 * j + 1] - bf2f(h1));
        H[j] = (unsigned int)h0 | ((unsigned int)h1 << 16);
        L[j] = (unsigned int)l0 | ((unsigned int)l1 << 16);
    }
    ((uint4*)xh)[i] = make_uint4(H[0], H[1], H[2], H[3]);
    ((uint4*)xl)[i] = make_uint4(L[0], L[1], L[2], L[3]);
}

// ---------------------------------------------------------------------------
// W[K][F] fp32 -> Th[dstRow0+f][k], Tl[...] bf16 split (transposed, K-contig)
// ---------------------------------------------------------------------------
__global__ __launch_bounds__(256) void transpose_split_kernel(
    const float* __restrict__ W, unsigned short* __restrict__ Th, unsigned short* __restrict__ Tl,
    int K, int F, int dstRow0, int dstStride) {
    __shared__ float tile[32][33];
    const int k0 = blockIdx.x * 32, f0 = blockIdx.y * 32;
    const int tx = threadIdx.x, ty = threadIdx.y;  // 32 x 8
#pragma unroll
    for (int i = 0; i < 4; i++) {
        int kk = ty + 8 * i;
        tile[kk][tx] = W[(size_t)(k0 + kk) * F + f0 + tx];
    }
    __syncthreads();
#pragma unroll
    for (int i = 0; i < 4; i++) {
        int ff = ty + 8 * i;
        float v = tile[tx][ff];
        unsigned short h = f2bf(v);
        size_t o = (size_t)(dstRow0 + f0 + ff) * dstStride + k0 + tx;
        Th[o] = h;
        Tl[o] = f2bf(v - bf2f(h));
    }
}

__global__ void bias_pack_kernel(const float* __restrict__ bk, const float* __restrict__ bq,
                                 const float* __restrict__ bv, float* __restrict__ bkqv) {
    int i = threadIdx.x + blockIdx.x * blockDim.x;
    if (i < 256) bkqv[i] = bk[i];
    else if (i < 512) bkqv[i] = bq[i - 256];
    else if (i < 768) bkqv[i] = bv[i - 512];
}

// ---------------------------------------------------------------------------
// Split-bf16 MFMA GEMM: C[M,F] = A(hi+lo)[M,K] @ B(hi+lo)^T-stored[F,K] + bias
// Tile 128x128, BK=32, 256 threads = 4 waves (2x2), 4x4 frags of 16x16x32.
// OUT_MODE: 0 = bf16 (KQV), 1 = bf16 hi/lo pair (Wa), 2 = fp32 + resid (Wf)
// ---------------------------------------------------------------------------
template<int OUT_MODE, bool RELU>
__global__ __launch_bounds__(256, 2) void gemm_bf16x3_kernel(
    const unsigned short* __restrict__ Ahi, const unsigned short* __restrict__ Alo,
    const unsigned short* __restrict__ Bhi, const unsigned short* __restrict__ Blo,
    const float* __restrict__ bias, const float* __restrict__ resid,
    void* __restrict__ outp, unsigned short* __restrict__ out_lo,
    int Mrows, int Ktot, int F)
{
    __shared__ unsigned short sm[2][4 * 4096];  // [buf][Ah|Al|Bh|Bl][128*32]

    const int tid = threadIdx.x;
    const int wid = tid >> 6, lane = tid & 63;
    const int wm = wid >> 1, wn = wid & 1;
    const int l15 = lane & 15, kw = lane >> 4;
    const int brow = blockIdx.y * 128, bcol = blockIdx.x * 128;
    const int Mm1 = Mrows - 1;

    // staging descriptors: 32 chunks of 1KB (16 rows x 64B); wave w takes w+4i
    const unsigned short* srcs[8];
    int ldsoff[8];
    {
        const int rl = lane >> 2, slot = lane & 3;
#pragma unroll
        for (int i = 0; i < 8; i++) {
            int c = wid + i * 4;
            int s = c >> 3, q = c & 7;
            int row = q * 16 + rl;
            int swz = (slot ^ ((row >> 1) & 3)) * 8;  // pre-swizzled source slot
            const unsigned short* base;
            if (s == 0) { int rg = brow + row; if (rg > Mm1) rg = Mm1; base = Ahi + (size_t)rg * Ktot + swz; }
            else if (s == 1) { int rg = brow + row; if (rg > Mm1) rg = Mm1; base = Alo + (size_t)rg * Ktot + swz; }
            else if (s == 2) { base = Bhi + (size_t)(bcol + row) * Ktot + swz; }
            else             { base = Blo + (size_t)(bcol + row) * Ktot + swz; }
            srcs[i] = base;
            ldsoff[i] = s * 4096 + q * 512;
        }
    }

    f32x4 acc[4][4];
#pragma unroll
    for (int a = 0; a < 4; a++)
#pragma unroll
        for (int b = 0; b < 4; b++) acc[a][b] = (f32x4){0.f, 0.f, 0.f, 0.f};

    // fragment read offsets (swizzled to match staged layout)
    int aoff[4], boff[4];
#pragma unroll
    for (int f = 0; f < 4; f++) {
        int r = wm * 64 + f * 16 + l15;
        aoff[f] = r * 32 + ((kw ^ ((r >> 1) & 3)) << 3);
        int cn = wn * 64 + f * 16 + l15;
        boff[f] = cn * 32 + ((kw ^ ((cn >> 1) & 3)) << 3);
    }

    const int nt = Ktot / 32;
    // prologue: stage tile 0 into buf 0
#pragma unroll
    for (int i = 0; i < 8; i++) gld_lds16(srcs[i], &sm[0][ldsoff[i]]);
    __syncthreads();

    for (int t = 0; t < nt; t++) {
        const unsigned short* sb = &sm[t & 1][0];
        if (t + 1 < nt) {
            unsigned short* db = &sm[(t + 1) & 1][0];
            const int k0 = (t + 1) * 32;
#pragma unroll
            for (int i = 0; i < 8; i++) gld_lds16(srcs[i] + k0, &db[ldsoff[i]]);
        }
        bf16x8v ah[4], al[4], bh[4], bl[4];
#pragma unroll
        for (int f = 0; f < 4; f++) {
            ah[f] = *(const bf16x8v*)&sb[aoff[f]];
            al[f] = *(const bf16x8v*)&sb[4096 + aoff[f]];
            bh[f] = *(const bf16x8v*)&sb[2 * 4096 + boff[f]];
            bl[f] = *(const bf16x8v*)&sb[3 * 4096 + boff[f]];
        }
#pragma unroll
        for (int fr = 0; fr < 4; fr++)
#pragma unroll
            for (int fc = 0; fc < 4; fc++) {
                acc[fr][fc] = __builtin_amdgcn_mfma_f32_16x16x32_bf16(ah[fr], bh[fc], acc[fr][fc], 0, 0, 0);
                acc[fr][fc] = __builtin_amdgcn_mfma_f32_16x16x32_bf16(ah[fr], bl[fc], acc[fr][fc], 0, 0, 0);
                acc[fr][fc] = __builtin_amdgcn_mfma_f32_16x16x32_bf16(al[fr], bh[fc], acc[fr][fc], 0, 0, 0);
            }
        __syncthreads();
    }

    // epilogue: C row = (lane>>4)*4 + j, col = lane&15 (m89-verified layout)
    float bv4[4];
#pragma unroll
    for (int fc = 0; fc < 4; fc++) bv4[fc] = bias[bcol + wn * 64 + fc * 16 + l15];

#pragma unroll
    for (int fr = 0; fr < 4; fr++) {
#pragma unroll
        for (int j = 0; j < 4; j++) {
            const int row = brow + wm * 64 + fr * 16 + kw * 4 + j;
            if (row >= Mrows) continue;
#pragma unroll
            for (int fc = 0; fc < 4; fc++) {
                const int col = bcol + wn * 64 + fc * 16 + l15;
                float v = acc[fr][fc][j] + bv4[fc];
                if (RELU) v = fmaxf(v, 0.0f);
                const size_t o = (size_t)row * F + col;
                if (OUT_MODE == 0) {
                    ((unsigned short*)outp)[o] = f2bf(v);
                } else if (OUT_MODE == 1) {
                    unsigned short h = f2bf(v);
                    ((unsigned short*)outp)[o] = h;
                    out_lo[o] = f2bf(v - bf2f(h));
                } else {
                    ((float*)outp)[o] = v + resid[o];
                }
            }
        }
    }
}

// ---------------------------------------------------------------------------
// Attention gather over bf16 K|Q|V (combined [N][768]); writes agg hi/lo bf16
// ---------------------------------------------------------------------------
__global__ __launch_bounds__(256) void attn_kernel(
    const unsigned short* __restrict__ kqv,
    const int* __restrict__ rowptr, const int* __restrict__ ssend,
    unsigned short* __restrict__ agg_hi, unsigned short* __restrict__ agg_lo, int N)
{
    const int grp = threadIdx.x >> 5;
    const int lane = threadIdx.x & 31;
    const int p = blockIdx.x * 8 + grp;
    if (p >= N * HEADS) return;
    const int r = p >> 3;
    const int h = p & 7;

    const float qd = bf2f(kqv[(size_t)r * FKQV + 256 + h * DK + lane]);
    const float scale = 0.17677669529663687f;  // 1/sqrt(32)

    float accV = 0.0f, denom = 0.0f;
    const int beg = rowptr[r], end = rowptr[r + 1];
    for (int e = beg; e < end; e++) {
        const int s = ssend[e];
        const size_t base = (size_t)s * FKQV + h * DK;
        float t = qd * bf2f(kqv[base + lane]);
        t += __shfl_xor(t, 1);
        t += __shfl_xor(t, 2);
        t += __shfl_xor(t, 4);
        t += __shfl_xor(t, 8);
        t += __shfl_xor(t, 16);
        const float att = expf(t * scale);
        denom += att;
        accV = fmaf(att, bf2f(kqv[base + 512 + lane]), accV);
    }
    float o = (denom > 0.0f) ? (accV / denom) : 0.0f;
    o = fmaxf(o, 0.0f);
    unsigned short hi = f2bf(o);
    const size_t oo = (size_t)r * 256 + h * DK + lane;
    agg_hi[oo] = hi;
    agg_lo[oo] = f2bf(o - bf2f(hi));
}

// ---------------------------------------------------------------------------
extern "C" void kernel_launch(void* const* d_in, const int* in_sizes, int n_in,
                              void* d_out, int out_size, void* d_ws, size_t ws_size,
                              hipStream_t stream) {
    const float* x  = (const float*)d_in[0];
    const int* eidx = (const int*)d_in[1];
    const float* Wk = (const float*)d_in[2];
    const float* bk = (const float*)d_in[3];
    const float* Wq = (const float*)d_in[4];
    const float* bq = (const float*)d_in[5];
    const float* Wv = (const float*)d_in[6];
    const float* bv = (const float*)d_in[7];
    const float* Wa = (const float*)d_in[8];
    const float* ba = (const float*)d_in[9];
    const float* Wf = (const float*)d_in[10];
    const float* bf_ = (const float*)d_in[11];
    float* out = (float*)d_out;

    const int N = in_sizes[0] / D_EMB;   // 50000
    const int M = in_sizes[1] / 2;       // 400000
    const int* recv = eidx;
    const int* send = eidx + M;

    // ---- workspace layout (bytes) ----
    char* w = (char*)d_ws;
    unsigned short* x_hi = (unsigned short*)w;               // N*512
    unsigned short* x_lo = x_hi + (size_t)N * 512;           // N*512
    unsigned short* kqv  = x_lo + (size_t)N * 512;           // N*768
    unsigned short* wts  = kqv + (size_t)N * FKQV;
    unsigned short* Wkqv_hi = wts;                           // 768*512
    unsigned short* Wkqv_lo = Wkqv_hi + 768 * 512;
    unsigned short* Wat_hi  = Wkqv_lo + 768 * 512;           // 512*256
    unsigned short* Wat_lo  = Wat_hi + 512 * 256;
    unsigned short* Wft_hi  = Wat_lo + 512 * 256;            // 512*512
    unsigned short* Wft_lo  = Wft_hi + 512 * 512;
    float* b_kqv = (float*)(Wft_lo + 512 * 512);             // 768
    int* rowptr = (int*)(b_kqv + 768);                       // N+1
    int* cursor = rowptr + (N + 1);                          // N
    int* ssend  = cursor + N;                                // M
    // aliases (after KQV GEMM / attention, earlier buffers are dead):
    unsigned short* agg_hi = x_hi;                           // N*256 (x region)
    unsigned short* agg_lo = x_hi + (size_t)N * 256;         // N*256
    unsigned short* h1_lo  = x_lo;                           // N*512 (x region)
    unsigned short* h1_hi  = kqv;                            // N*512 (kqv region)

    // ---- CSR build ----
    hipMemsetAsync(cursor, 0, (size_t)N * sizeof(int), stream);
    count_deg_kernel<<<(M + 255) / 256, 256, 0, stream>>>(recv, cursor, M);
    scan_kernel<<<1, 1024, 0, stream>>>(cursor, rowptr, N);
    hipMemsetAsync(cursor, 0, (size_t)N * sizeof(int), stream);
    scatter_kernel<<<(M + 255) / 256, 256, 0, stream>>>(recv, send, rowptr, cursor, ssend, M);

    // ---- input split + weight prep ----
    split_x_kernel<<<((N * 512 / 8) + 255) / 256, 256, 0, stream>>>(x, x_hi, x_lo, N * 512 / 8);
    {
        dim3 b(32, 8);
        transpose_split_kernel<<<dim3(512 / 32, 256 / 32), b, 0, stream>>>(Wk, Wkqv_hi, Wkqv_lo, 512, 256, 0,   512);
        transpose_split_kernel<<<dim3(512 / 32, 256 / 32), b, 0, stream>>>(Wq, Wkqv_hi, Wkqv_lo, 512, 256, 256, 512);
        transpose_split_kernel<<<dim3(512 / 32, 256 / 32), b, 0, stream>>>(Wv, Wkqv_hi, Wkqv_lo, 512, 256, 512, 512);
        transpose_split_kernel<<<dim3(256 / 32, 512 / 32), b, 0, stream>>>(Wa, Wat_hi, Wat_lo, 256, 512, 0, 256);
        transpose_split_kernel<<<dim3(512 / 32, 512 / 32), b, 0, stream>>>(Wf, Wft_hi, Wft_lo, 512, 512, 0, 512);
    }
    bias_pack_kernel<<<3, 256, 0, stream>>>(bk, bq, bv, b_kqv);

    const int gy = (N + 127) / 128;  // 391

    // ---- KQV = x @ [Wk|Wq|Wv] + b  -> bf16 [N][768] ----
    gemm_bf16x3_kernel<0, false><<<dim3(FKQV / 128, gy), 256, 0, stream>>>(
        x_hi, x_lo, Wkqv_hi, Wkqv_lo, b_kqv, nullptr, kqv, nullptr, N, 512, FKQV);

    // ---- attention gather -> agg hi/lo (bf16 split) ----
    attn_kernel<<<(N * HEADS + 7) / 8, 256, 0, stream>>>(kqv, rowptr, ssend, agg_hi, agg_lo, N);

    // ---- h1 = relu(agg @ Wa + ba) -> bf16 hi/lo ----
    gemm_bf16x3_kernel<1, true><<<dim3(512 / 128, gy), 256, 0, stream>>>(
        agg_hi, agg_lo, Wat_hi, Wat_lo, ba, nullptr, h1_hi, h1_lo, N, 256, 512);

    // ---- out = x + relu(h1 @ Wf + bf) -> fp32 ----
    gemm_bf16x3_kernel<2, true><<<dim3(512 / 128, gy), 256, 0, stream>>>(
        h1_hi, h1_lo, Wft_hi, Wft_lo, bf_, x, out, nullptr, N, 512, 512);
}

// Round 4
// 548.755 us; speedup vs baseline: 2.7863x; 1.5618x over previous
//
#include <hip/hip_runtime.h>
#include <hip/hip_bf16.h>
#include <math.h>

#define D_EMB 512
#define HEADS 8
#define DK 32
#define FKQV 768   // K|Q|V combined output width

typedef __attribute__((ext_vector_type(8))) _Float16 f16x8;
typedef __attribute__((ext_vector_type(4))) float f32x4;

__device__ __forceinline__ unsigned short f2h(float f) {
    _Float16 h = (_Float16)f;
    return __builtin_bit_cast(unsigned short, h);
}
__device__ __forceinline__ float h2f(unsigned short u) {
    return (float)__builtin_bit_cast(_Float16, u);
}

__device__ __forceinline__ void gld_lds16(const void* g, void* l) {
    __builtin_amdgcn_global_load_lds(
        (const __attribute__((address_space(1))) unsigned int*)g,
        (__attribute__((address_space(3))) unsigned int*)l, 16, 0, 0);
}

// ---------------------------------------------------------------------------
// CSR build
// ---------------------------------------------------------------------------
__global__ void count_deg_kernel(const int* __restrict__ recv, int* __restrict__ deg, int M) {
    int e = blockIdx.x * blockDim.x + threadIdx.x;
    if (e < M) atomicAdd(&deg[recv[e]], 1);
}

// per-block inclusive scan (1024/block) -> rowptr[i+1] (pre-carry), bsum[b]
__global__ __launch_bounds__(1024) void scan_block_kernel(const int* __restrict__ deg,
                                                          int* __restrict__ rowptr,
                                                          int* __restrict__ bsum, int n) {
    __shared__ int buf[1024];
    const int i = blockIdx.x * 1024 + threadIdx.x;
    buf[threadIdx.x] = (i < n) ? deg[i] : 0;
    __syncthreads();
    for (int off = 1; off < 1024; off <<= 1) {
        int t = (threadIdx.x >= off) ? buf[threadIdx.x - off] : 0;
        __syncthreads();
        buf[threadIdx.x] += t;
        __syncthreads();
    }
    if (i < n) rowptr[i + 1] = buf[threadIdx.x];
    if (threadIdx.x == 1023) bsum[blockIdx.x] = buf[1023];
}

// exclusive scan of per-block sums (nb <= 64), one wave
__global__ void scan_carry_kernel(int* __restrict__ bsum, int* __restrict__ rowptr, int nb) {
    const int lane = threadIdx.x;  // 0..63
    int v = (lane < nb) ? bsum[lane] : 0;
    const int orig = v;
#pragma unroll
    for (int off = 1; off < 64; off <<= 1) {
        int t = __shfl_up(v, off, 64);
        if (lane >= off) v += t;
    }
    if (lane < nb) bsum[lane] = v - orig;  // exclusive carry
    if (lane == 0) rowptr[0] = 0;
}

__global__ void add_carry_kernel(int* __restrict__ rowptr, const int* __restrict__ bsum, int n) {
    int i = blockIdx.x * blockDim.x + threadIdx.x;
    if (i < n) rowptr[i + 1] += bsum[i >> 10];
}

__global__ void scatter_kernel(const int* __restrict__ recv, const int* __restrict__ send,
                               const int* __restrict__ rowptr, int* __restrict__ cursor,
                               int* __restrict__ ssend, int M) {
    int e = blockIdx.x * blockDim.x + threadIdx.x;
    if (e < M) {
        int r = recv[e];
        int pos = atomicAdd(&cursor[r], 1);
        ssend[rowptr[r] + pos] = send[e];
    }
}

// ---------------------------------------------------------------------------
// x (fp32) -> fp16, 8 elems/thread
// ---------------------------------------------------------------------------
__global__ void cvt_x_kernel(const float* __restrict__ x, unsigned short* __restrict__ xh, int n8) {
    int i = blockIdx.x * blockDim.x + threadIdx.x;
    if (i >= n8) return;
    const float4 a = ((const float4*)x)[2 * i];
    const float4 b = ((const float4*)x)[2 * i + 1];
    const float v[8] = {a.x, a.y, a.z, a.w, b.x, b.y, b.z, b.w};
    unsigned int u[4];
#pragma unroll
    for (int j = 0; j < 4; j++)
        u[j] = (unsigned int)f2h(v[2 * j]) | ((unsigned int)f2h(v[2 * j + 1]) << 16);
    ((uint4*)xh)[i] = make_uint4(u[0], u[1], u[2], u[3]);
}

// ---------------------------------------------------------------------------
// W[K][F] fp32 -> Th[dstRow0+f][k], Tl[...] fp16 hi/lo (transposed, K-contig)
// ---------------------------------------------------------------------------
__global__ __launch_bounds__(256) void transpose_split_kernel(
    const float* __restrict__ W, unsigned short* __restrict__ Th, unsigned short* __restrict__ Tl,
    int K, int F, int dstRow0, int dstStride) {
    __shared__ float tile[32][33];
    const int k0 = blockIdx.x * 32, f0 = blockIdx.y * 32;
    const int tx = threadIdx.x, ty = threadIdx.y;  // 32 x 8
#pragma unroll
    for (int i = 0; i < 4; i++) {
        int kk = ty + 8 * i;
        tile[kk][tx] = W[(size_t)(k0 + kk) * F + f0 + tx];
    }
    __syncthreads();
#pragma unroll
    for (int i = 0; i < 4; i++) {
        int ff = ty + 8 * i;
        float v = tile[tx][ff];
        unsigned short h = f2h(v);
        size_t o = (size_t)(dstRow0 + f0 + ff) * dstStride + k0 + tx;
        Th[o] = h;
        Tl[o] = f2h(v - h2f(h));
    }
}

__global__ void bias_pack_kernel(const float* __restrict__ bk, const float* __restrict__ bq,
                                 const float* __restrict__ bv, float* __restrict__ bkqv) {
    int i = threadIdx.x + blockIdx.x * blockDim.x;
    if (i < 256) bkqv[i] = bk[i];
    else if (i < 512) bkqv[i] = bq[i - 256];
    else if (i < 768) bkqv[i] = bv[i - 512];
}

// ---------------------------------------------------------------------------
// fp16 2-term MFMA GEMM: C = A[M,K] @ (Bhi+Blo)^T-stored[F,K] + bias
// Tile 128x128, BK=32, 4 waves (2x2), 4x4 frags of 16x16x32_f16.
// OUT_MODE: 0 = fp16 out, 2 = fp32 + resid
// ---------------------------------------------------------------------------
template<int OUT_MODE, bool RELU>
__global__ __launch_bounds__(256, 2) void gemm_f16_kernel(
    const unsigned short* __restrict__ A,
    const unsigned short* __restrict__ Bhi, const unsigned short* __restrict__ Blo,
    const float* __restrict__ bias, const float* __restrict__ resid,
    void* __restrict__ outp, int Mrows, int Ktot, int F)
{
    __shared__ unsigned short sm[2][3 * 4096];  // [buf][A|Bh|Bl][128*32]

    const int tid = threadIdx.x;
    const int wid = tid >> 6, lane = tid & 63;
    const int wm = wid >> 1, wn = wid & 1;
    const int l15 = lane & 15, kw = lane >> 4;
    const int brow = blockIdx.y * 128, bcol = blockIdx.x * 128;
    const int Mm1 = Mrows - 1;

    // staging: 24 chunks of 1KB (16 rows x 64B); wave w takes chunks w+4i
    const unsigned short* srcs[6];
    int ldsoff[6];
    {
        const int rl = lane >> 2, slot = lane & 3;
#pragma unroll
        for (int i = 0; i < 6; i++) {
            int c = wid + i * 4;
            int s = c >> 3, q = c & 7;
            int row = q * 16 + rl;
            int swz = (slot ^ ((row >> 1) & 3)) * 8;  // pre-swizzled source slot
            const unsigned short* base;
            if (s == 0) { int rg = brow + row; if (rg > Mm1) rg = Mm1; base = A + (size_t)rg * Ktot + swz; }
            else if (s == 1) { base = Bhi + (size_t)(bcol + row) * Ktot + swz; }
            else             { base = Blo + (size_t)(bcol + row) * Ktot + swz; }
            srcs[i] = base;
            ldsoff[i] = s * 4096 + q * 512;
        }
    }

    f32x4 acc[4][4];
#pragma unroll
    for (int a = 0; a < 4; a++)
#pragma unroll
        for (int b = 0; b < 4; b++) acc[a][b] = (f32x4){0.f, 0.f, 0.f, 0.f};

    int aoff[4], boff[4];
#pragma unroll
    for (int f = 0; f < 4; f++) {
        int r = wm * 64 + f * 16 + l15;
        aoff[f] = r * 32 + ((kw ^ ((r >> 1) & 3)) << 3);
        int cn = wn * 64 + f * 16 + l15;
        boff[f] = cn * 32 + ((kw ^ ((cn >> 1) & 3)) << 3);
    }

    const int nt = Ktot / 32;
#pragma unroll
    for (int i = 0; i < 6; i++) gld_lds16(srcs[i], &sm[0][ldsoff[i]]);
    __syncthreads();

    for (int t = 0; t < nt; t++) {
        const unsigned short* sb = &sm[t & 1][0];
        if (t + 1 < nt) {
            unsigned short* db = &sm[(t + 1) & 1][0];
            const int k0 = (t + 1) * 32;
#pragma unroll
            for (int i = 0; i < 6; i++) gld_lds16(srcs[i] + k0, &db[ldsoff[i]]);
        }
        f16x8 ah[4], bh[4], bl[4];
#pragma unroll
        for (int f = 0; f < 4; f++) {
            ah[f] = *(const f16x8*)&sb[aoff[f]];
            bh[f] = *(const f16x8*)&sb[4096 + boff[f]];
            bl[f] = *(const f16x8*)&sb[2 * 4096 + boff[f]];
        }
#pragma unroll
        for (int fr = 0; fr < 4; fr++)
#pragma unroll
            for (int fc = 0; fc < 4; fc++) {
                acc[fr][fc] = __builtin_amdgcn_mfma_f32_16x16x32_f16(ah[fr], bh[fc], acc[fr][fc], 0, 0, 0);
                acc[fr][fc] = __builtin_amdgcn_mfma_f32_16x16x32_f16(ah[fr], bl[fc], acc[fr][fc], 0, 0, 0);
            }
        __syncthreads();
    }

    // epilogue: C row = kw*4 + j (within 16), col = l15
    float bv4[4];
#pragma unroll
    for (int fc = 0; fc < 4; fc++) bv4[fc] = bias[bcol + wn * 64 + fc * 16 + l15];

#pragma unroll
    for (int fr = 0; fr < 4; fr++) {
#pragma unroll
        for (int j = 0; j < 4; j++) {
            const int row = brow + wm * 64 + fr * 16 + kw * 4 + j;
            if (row >= Mrows) continue;
#pragma unroll
            for (int fc = 0; fc < 4; fc++) {
                const int col = bcol + wn * 64 + fc * 16 + l15;
                float v = acc[fr][fc][j] + bv4[fc];
                if (RELU) v = fmaxf(v, 0.0f);
                const size_t o = (size_t)row * F + col;
                if (OUT_MODE == 0) {
                    ((unsigned short*)outp)[o] = f2h(v);
                } else {
                    ((float*)outp)[o] = v + resid[o];
                }
            }
        }
    }
}

// ---------------------------------------------------------------------------
// Fused attention: one lane per (receiver, head). Q in regs, 32-float acc in
// regs, per-edge vector loads of K/V (8x16B), no cross-lane ops.
// agg[r,h*32+d] = relu( (sum_e exp(q.k*s) * V) / sum_e exp(q.k*s) )  (fp16)
// ---------------------------------------------------------------------------
__global__ __launch_bounds__(256) void attn_fused_kernel(
    const unsigned short* __restrict__ kqv, const int* __restrict__ rowptr,
    const int* __restrict__ ssend, unsigned short* __restrict__ agg, int N)
{
    const int idx = blockIdx.x * 256 + threadIdx.x;
    const int r = idx >> 3;
    if (r >= N) return;
    const int h = idx & 7;

    const unsigned short* qp = kqv + (size_t)r * FKQV + 256 + h * 32;
    const f16x8 q0 = *(const f16x8*)(qp);
    const f16x8 q1 = *(const f16x8*)(qp + 8);
    const f16x8 q2 = *(const f16x8*)(qp + 16);
    const f16x8 q3 = *(const f16x8*)(qp + 24);

    float acc[4][8];
#pragma unroll
    for (int j = 0; j < 4; j++)
#pragma unroll
        for (int i = 0; i < 8; i++) acc[j][i] = 0.0f;
    float denom = 0.0f;

    const int e0 = rowptr[r], e1 = rowptr[r + 1];
    const float scale = 0.17677669529663687f;  // 1/sqrt(32)

    for (int e = e0; e < e1; ++e) {
        const int s = ssend[e];
        const unsigned short* kp = kqv + (size_t)s * FKQV + h * 32;
        const f16x8 k0 = *(const f16x8*)(kp);
        const f16x8 k1 = *(const f16x8*)(kp + 8);
        const f16x8 k2 = *(const f16x8*)(kp + 16);
        const f16x8 k3 = *(const f16x8*)(kp + 24);
        const f16x8 v0 = *(const f16x8*)(kp + 512);
        const f16x8 v1 = *(const f16x8*)(kp + 520);
        const f16x8 v2 = *(const f16x8*)(kp + 528);
        const f16x8 v3 = *(const f16x8*)(kp + 536);

        float d0 = 0.f, d1 = 0.f, d2 = 0.f, d3 = 0.f;
#pragma unroll
        for (int i = 0; i < 8; i++) {
            d0 = fmaf((float)q0[i], (float)k0[i], d0);
            d1 = fmaf((float)q1[i], (float)k1[i], d1);
            d2 = fmaf((float)q2[i], (float)k2[i], d2);
            d3 = fmaf((float)q3[i], (float)k3[i], d3);
        }
        const float a = __expf(((d0 + d1) + (d2 + d3)) * scale);
        denom += a;
#pragma unroll
        for (int i = 0; i < 8; i++) {
            acc[0][i] = fmaf(a, (float)v0[i], acc[0][i]);
            acc[1][i] = fmaf(a, (float)v1[i], acc[1][i]);
            acc[2][i] = fmaf(a, (float)v2[i], acc[2][i]);
            acc[3][i] = fmaf(a, (float)v3[i], acc[3][i]);
        }
    }

    const float inv = (e1 > e0) ? (1.0f / denom) : 0.0f;
    unsigned short* op = agg + (size_t)r * 256 + h * 32;
#pragma unroll
    for (int j = 0; j < 4; j++) {
        f16x8 ov;
#pragma unroll
        for (int i = 0; i < 8; i++) ov[i] = (_Float16)fmaxf(acc[j][i] * inv, 0.0f);
        *(f16x8*)(op + j * 8) = ov;
    }
}

// ---------------------------------------------------------------------------
extern "C" void kernel_launch(void* const* d_in, const int* in_sizes, int n_in,
                              void* d_out, int out_size, void* d_ws, size_t ws_size,
                              hipStream_t stream) {
    const float* x  = (const float*)d_in[0];
    const int* eidx = (const int*)d_in[1];
    const float* Wk = (const float*)d_in[2];
    const float* bk = (const float*)d_in[3];
    const float* Wq = (const float*)d_in[4];
    const float* bq = (const float*)d_in[5];
    const float* Wv = (const float*)d_in[6];
    const float* bv = (const float*)d_in[7];
    const float* Wa = (const float*)d_in[8];
    const float* ba = (const float*)d_in[9];
    const float* Wf = (const float*)d_in[10];
    const float* bf_ = (const float*)d_in[11];
    float* out = (float*)d_out;

    const int N = in_sizes[0] / D_EMB;   // 50000
    const int M = in_sizes[1] / 2;       // 400000
    const int* recv = eidx;
    const int* send = eidx + M;

    // ---- workspace layout ----
    unsigned short* x_h = (unsigned short*)d_ws;             // N*512
    unsigned short* kqv = x_h + (size_t)N * 512;             // N*768
    unsigned short* agg = kqv + (size_t)N * FKQV;            // N*256
    unsigned short* Wkqv_hi = agg + (size_t)N * 256;         // 768*512
    unsigned short* Wkqv_lo = Wkqv_hi + 768 * 512;
    unsigned short* Wat_hi  = Wkqv_lo + 768 * 512;           // 512*256
    unsigned short* Wat_lo  = Wat_hi + 512 * 256;
    unsigned short* Wft_hi  = Wat_lo + 512 * 256;            // 512*512
    unsigned short* Wft_lo  = Wft_hi + 512 * 512;
    float* b_kqv = (float*)(Wft_lo + 512 * 512);             // 768
    int* rowptr = (int*)(b_kqv + 768);                       // N+1
    int* cursor = rowptr + (N + 1);                          // N
    int* bsum   = cursor + N;                                // 64
    int* ssend  = bsum + 64;                                 // M
    unsigned short* h1 = x_h;                                // alias: x_h dead after KQV GEMM

    const int nb = (N + 1023) / 1024;  // 49

    // ---- CSR build ----
    hipMemsetAsync(cursor, 0, (size_t)N * sizeof(int), stream);
    count_deg_kernel<<<(M + 255) / 256, 256, 0, stream>>>(recv, cursor, M);
    scan_block_kernel<<<nb, 1024, 0, stream>>>(cursor, rowptr, bsum, N);
    scan_carry_kernel<<<1, 64, 0, stream>>>(bsum, rowptr, nb);
    add_carry_kernel<<<(N + 255) / 256, 256, 0, stream>>>(rowptr, bsum, N);
    hipMemsetAsync(cursor, 0, (size_t)N * sizeof(int), stream);
    scatter_kernel<<<(M + 255) / 256, 256, 0, stream>>>(recv, send, rowptr, cursor, ssend, M);

    // ---- input cvt + weight prep ----
    cvt_x_kernel<<<((N * 512 / 8) + 255) / 256, 256, 0, stream>>>(x, x_h, N * 512 / 8);
    {
        dim3 b(32, 8);
        transpose_split_kernel<<<dim3(16, 8), b, 0, stream>>>(Wk, Wkqv_hi, Wkqv_lo, 512, 256, 0,   512);
        transpose_split_kernel<<<dim3(16, 8), b, 0, stream>>>(Wq, Wkqv_hi, Wkqv_lo, 512, 256, 256, 512);
        transpose_split_kernel<<<dim3(16, 8), b, 0, stream>>>(Wv, Wkqv_hi, Wkqv_lo, 512, 256, 512, 512);
        transpose_split_kernel<<<dim3(8, 16), b, 0, stream>>>(Wa, Wat_hi, Wat_lo, 256, 512, 0, 256);
        transpose_split_kernel<<<dim3(16, 16), b, 0, stream>>>(Wf, Wft_hi, Wft_lo, 512, 512, 0, 512);
    }
    bias_pack_kernel<<<3, 256, 0, stream>>>(bk, bq, bv, b_kqv);

    const int gy = (N + 127) / 128;  // 391

    // ---- KQV = x @ [Wk|Wq|Wv] + b -> fp16 [N][768] ----
    gemm_f16_kernel<0, false><<<dim3(FKQV / 128, gy), 256, 0, stream>>>(
        x_h, Wkqv_hi, Wkqv_lo, b_kqv, nullptr, kqv, N, 512, FKQV);

    // ---- fused attention gather -> agg fp16 [N][256] ----
    attn_fused_kernel<<<(N * HEADS + 255) / 256, 256, 0, stream>>>(kqv, rowptr, ssend, agg, N);

    // ---- h1 = relu(agg @ Wa + ba) -> fp16 [N][512] ----
    gemm_f16_kernel<0, true><<<dim3(4, gy), 256, 0, stream>>>(
        agg, Wat_hi, Wat_lo, ba, nullptr, h1, N, 256, 512);

    // ---- out = x + relu(h1 @ Wf + bf) -> fp32 ----
    gemm_f16_kernel<2, true><<<dim3(4, gy), 256, 0, stream>>>(
        h1, Wft_hi, Wft_lo, bf_, x, out, N, 512, 512);
}

// Round 6
// 479.411 us; speedup vs baseline: 3.1893x; 1.1446x over previous
//
#include <hip/hip_runtime.h>
#include <hip/hip_bf16.h>
#include <math.h>

#define D_EMB 512
#define HEADS 8
#define DK 32
#define FKQV 768   // K|Q|V combined output width

typedef __attribute__((ext_vector_type(8))) _Float16 f16x8;
typedef __attribute__((ext_vector_type(4))) float f32x4;

__device__ __forceinline__ unsigned short f2h(float f) {
    _Float16 h = (_Float16)f;
    return __builtin_bit_cast(unsigned short, h);
}
__device__ __forceinline__ float h2f(unsigned short u) {
    return (float)__builtin_bit_cast(_Float16, u);
}

__device__ __forceinline__ void gld_lds16(const void* g, void* l) {
    __builtin_amdgcn_global_load_lds(
        (const __attribute__((address_space(1))) unsigned int*)g,
        (__attribute__((address_space(3))) unsigned int*)l, 16, 0, 0);
}

// ---------------------------------------------------------------------------
// CSR build
// ---------------------------------------------------------------------------
__global__ void count_deg_kernel(const int* __restrict__ recv, int* __restrict__ deg, int M) {
    int e = blockIdx.x * blockDim.x + threadIdx.x;
    if (e < M) atomicAdd(&deg[recv[e]], 1);
}

// per-block inclusive scan (1024/block) -> rowptr[i+1] (pre-carry), bsum[b]
__global__ __launch_bounds__(1024) void scan_block_kernel(const int* __restrict__ deg,
                                                          int* __restrict__ rowptr,
                                                          int* __restrict__ bsum, int n) {
    __shared__ int buf[1024];
    const int i = blockIdx.x * 1024 + threadIdx.x;
    buf[threadIdx.x] = (i < n) ? deg[i] : 0;
    __syncthreads();
    for (int off = 1; off < 1024; off <<= 1) {
        int t = (threadIdx.x >= off) ? buf[threadIdx.x - off] : 0;
        __syncthreads();
        buf[threadIdx.x] += t;
        __syncthreads();
    }
    if (i < n) rowptr[i + 1] = buf[threadIdx.x];
    if (threadIdx.x == 1023) bsum[blockIdx.x] = buf[1023];
}

// exclusive scan of per-block sums (nb <= 64), one wave
__global__ void scan_carry_kernel(int* __restrict__ bsum, int* __restrict__ rowptr, int nb) {
    const int lane = threadIdx.x;  // 0..63
    int v = (lane < nb) ? bsum[lane] : 0;
    const int orig = v;
#pragma unroll
    for (int off = 1; off < 64; off <<= 1) {
        int t = __shfl_up(v, off, 64);
        if (lane >= off) v += t;
    }
    if (lane < nb) bsum[lane] = v - orig;  // exclusive carry
    if (lane == 0) rowptr[0] = 0;
}

__global__ void add_carry_kernel(int* __restrict__ rowptr, const int* __restrict__ bsum, int n) {
    int i = blockIdx.x * blockDim.x + threadIdx.x;
    if (i < n) rowptr[i + 1] += bsum[i >> 10];
}

__global__ void scatter_kernel(const int* __restrict__ recv, const int* __restrict__ send,
                               const int* __restrict__ rowptr, int* __restrict__ cursor,
                               int* __restrict__ ssend, int M) {
    int e = blockIdx.x * blockDim.x + threadIdx.x;
    if (e < M) {
        int r = recv[e];
        int pos = atomicAdd(&cursor[r], 1);
        ssend[rowptr[r] + pos] = send[e];
    }
}

// ---------------------------------------------------------------------------
// x (fp32) -> fp16, 8 elems/thread
// ---------------------------------------------------------------------------
__global__ void cvt_x_kernel(const float* __restrict__ x, unsigned short* __restrict__ xh, int n8) {
    int i = blockIdx.x * blockDim.x + threadIdx.x;
    if (i >= n8) return;
    const float4 a = ((const float4*)x)[2 * i];
    const float4 b = ((const float4*)x)[2 * i + 1];
    const float v[8] = {a.x, a.y, a.z, a.w, b.x, b.y, b.z, b.w};
    unsigned int u[4];
#pragma unroll
    for (int j = 0; j < 4; j++)
        u[j] = (unsigned int)f2h(v[2 * j]) | ((unsigned int)f2h(v[2 * j + 1]) << 16);
    ((uint4*)xh)[i] = make_uint4(u[0], u[1], u[2], u[3]);
}

// ---------------------------------------------------------------------------
// W[K][F] fp32 -> T[dstRow0+f][k] fp16 (transposed, K-contiguous)
// ---------------------------------------------------------------------------
__global__ __launch_bounds__(256) void transpose_cvt_kernel(
    const float* __restrict__ W, unsigned short* __restrict__ T,
    int K, int F, int dstRow0, int dstStride) {
    __shared__ float tile[32][33];
    const int k0 = blockIdx.x * 32, f0 = blockIdx.y * 32;
    const int tx = threadIdx.x, ty = threadIdx.y;  // 32 x 8
#pragma unroll
    for (int i = 0; i < 4; i++) {
        int kk = ty + 8 * i;
        tile[kk][tx] = W[(size_t)(k0 + kk) * F + f0 + tx];
    }
    __syncthreads();
#pragma unroll
    for (int i = 0; i < 4; i++) {
        int ff = ty + 8 * i;
        T[(size_t)(dstRow0 + f0 + ff) * dstStride + k0 + tx] = f2h(tile[tx][ff]);
    }
}

__global__ void bias_pack_kernel(const float* __restrict__ bk, const float* __restrict__ bq,
                                 const float* __restrict__ bv, float* __restrict__ bkqv) {
    int i = threadIdx.x + blockIdx.x * blockDim.x;
    if (i < 256) bkqv[i] = bk[i];
    else if (i < 512) bkqv[i] = bq[i - 256];
    else if (i < 768) bkqv[i] = bv[i - 512];
}

// ---------------------------------------------------------------------------
// fp16 MFMA GEMM: C = A[M,K] @ B^T-stored[F,K] + bias
// Tile 128x128, BK=32, 4 waves (2x2), 4x4 frags of 16x16x32_f16.
// OUT_MODE: 0 = fp16 out, 2 = fp32 out + fp16 resid
// ---------------------------------------------------------------------------
template<int OUT_MODE, bool RELU>
__global__ __launch_bounds__(256, 4) void gemm_f16_kernel(
    const unsigned short* __restrict__ A, const unsigned short* __restrict__ B,
    const float* __restrict__ bias, const unsigned short* __restrict__ resid,
    void* __restrict__ outp, int Mrows, int Ktot, int F)
{
    __shared__ unsigned short sm[2][2 * 4096];  // [buf][A|B][128*32]

    const int tid = threadIdx.x;
    const int wid = tid >> 6, lane = tid & 63;
    const int wm = wid >> 1, wn = wid & 1;
    const int l15 = lane & 15, kw = lane >> 4;
    const int brow = blockIdx.y * 128, bcol = blockIdx.x * 128;
    const int Mm1 = Mrows - 1;

    // staging: 16 chunks of 1KB (16 rows x 64B); wave w takes chunks w+4i
    const unsigned short* srcs[4];
    int ldsoff[4];
    {
        const int rl = lane >> 2, slot = lane & 3;
#pragma unroll
        for (int i = 0; i < 4; i++) {
            int c = wid + i * 4;
            int s = c >> 3, q = c & 7;
            int row = q * 16 + rl;
            int swz = (slot ^ ((row >> 1) & 3)) * 8;  // pre-swizzled source slot
            const unsigned short* base;
            if (s == 0) { int rg = brow + row; if (rg > Mm1) rg = Mm1; base = A + (size_t)rg * Ktot + swz; }
            else        { base = B + (size_t)(bcol + row) * Ktot + swz; }
            srcs[i] = base;
            ldsoff[i] = s * 4096 + q * 512;
        }
    }

    f32x4 acc[4][4];
#pragma unroll
    for (int a = 0; a < 4; a++)
#pragma unroll
        for (int b = 0; b < 4; b++) acc[a][b] = (f32x4){0.f, 0.f, 0.f, 0.f};

    int aoff[4], boff[4];
#pragma unroll
    for (int f = 0; f < 4; f++) {
        int r = wm * 64 + f * 16 + l15;
        aoff[f] = r * 32 + ((kw ^ ((r >> 1) & 3)) << 3);
        int cn = wn * 64 + f * 16 + l15;
        boff[f] = cn * 32 + ((kw ^ ((cn >> 1) & 3)) << 3);
    }

    const int nt = Ktot / 32;
#pragma unroll
    for (int i = 0; i < 4; i++) gld_lds16(srcs[i], &sm[0][ldsoff[i]]);
    __syncthreads();

    for (int t = 0; t < nt; t++) {
        const unsigned short* sb = &sm[t & 1][0];
        if (t + 1 < nt) {
            unsigned short* db = &sm[(t + 1) & 1][0];
            const int k0 = (t + 1) * 32;
#pragma unroll
            for (int i = 0; i < 4; i++) gld_lds16(srcs[i] + k0, &db[ldsoff[i]]);
        }
        f16x8 ah[4], bh[4];
#pragma unroll
        for (int f = 0; f < 4; f++) {
            ah[f] = *(const f16x8*)&sb[aoff[f]];
            bh[f] = *(const f16x8*)&sb[4096 + boff[f]];
        }
#pragma unroll
        for (int fr = 0; fr < 4; fr++)
#pragma unroll
            for (int fc = 0; fc < 4; fc++)
                acc[fr][fc] = __builtin_amdgcn_mfma_f32_16x16x32_f16(ah[fr], bh[fc], acc[fr][fc], 0, 0, 0);
        __syncthreads();
    }

    // epilogue: C row = kw*4 + j (within 16), col = l15
    float bv4[4];
#pragma unroll
    for (int fc = 0; fc < 4; fc++) bv4[fc] = bias[bcol + wn * 64 + fc * 16 + l15];

#pragma unroll
    for (int fr = 0; fr < 4; fr++) {
#pragma unroll
        for (int j = 0; j < 4; j++) {
            const int row = brow + wm * 64 + fr * 16 + kw * 4 + j;
            if (row >= Mrows) continue;
#pragma unroll
            for (int fc = 0; fc < 4; fc++) {
                const int col = bcol + wn * 64 + fc * 16 + l15;
                float v = acc[fr][fc][j] + bv4[fc];
                if (RELU) v = fmaxf(v, 0.0f);
                const size_t o = (size_t)row * F + col;
                if (OUT_MODE == 0) {
                    ((unsigned short*)outp)[o] = f2h(v);
                } else {
                    ((float*)outp)[o] = v + h2f(resid[o]);
                }
            }
        }
    }
}

// ---------------------------------------------------------------------------
// Fused attention: one lane per (receiver, head). Q in regs, 32-float acc in
// regs, per-edge vector loads of K/V (8x16B), no cross-lane ops.
// ---------------------------------------------------------------------------
__global__ __launch_bounds__(256) void attn_fused_kernel(
    const unsigned short* __restrict__ kqv, const int* __restrict__ rowptr,
    const int* __restrict__ ssend, unsigned short* __restrict__ agg, int N)
{
    const int idx = blockIdx.x * 256 + threadIdx.x;
    const int r = idx >> 3;
    if (r >= N) return;
    const int h = idx & 7;

    const unsigned short* qp = kqv + (size_t)r * FKQV + 256 + h * 32;
    const f16x8 q0 = *(const f16x8*)(qp);
    const f16x8 q1 = *(const f16x8*)(qp + 8);
    const f16x8 q2 = *(const f16x8*)(qp + 16);
    const f16x8 q3 = *(const f16x8*)(qp + 24);

    float acc[4][8];
#pragma unroll
    for (int j = 0; j < 4; j++)
#pragma unroll
        for (int i = 0; i < 8; i++) acc[j][i] = 0.0f;
    float denom = 0.0f;

    const int e0 = rowptr[r], e1 = rowptr[r + 1];
    const float scale = 0.17677669529663687f;  // 1/sqrt(32)

    for (int e = e0; e < e1; ++e) {
        const int s = ssend[e];
        const unsigned short* kp = kqv + (size_t)s * FKQV + h * 32;
        const f16x8 k0 = *(const f16x8*)(kp);
        const f16x8 k1 = *(const f16x8*)(kp + 8);
        const f16x8 k2 = *(const f16x8*)(kp + 16);
        const f16x8 k3 = *(const f16x8*)(kp + 24);
        const f16x8 v0 = *(const f16x8*)(kp + 512);
        const f16x8 v1 = *(const f16x8*)(kp + 520);
        const f16x8 v2 = *(const f16x8*)(kp + 528);
        const f16x8 v3 = *(const f16x8*)(kp + 536);

        float d0 = 0.f, d1 = 0.f, d2 = 0.f, d3 = 0.f;
#pragma unroll
        for (int i = 0; i < 8; i++) {
            d0 = fmaf((float)q0[i], (float)k0[i], d0);
            d1 = fmaf((float)q1[i], (float)k1[i], d1);
            d2 = fmaf((float)q2[i], (float)k2[i], d2);
            d3 = fmaf((float)q3[i], (float)k3[i], d3);
        }
        const float a = __expf(((d0 + d1) + (d2 + d3)) * scale);
        denom += a;
#pragma unroll
        for (int i = 0; i < 8; i++) {
            acc[0][i] = fmaf(a, (float)v0[i], acc[0][i]);
            acc[1][i] = fmaf(a, (float)v1[i], acc[1][i]);
            acc[2][i] = fmaf(a, (float)v2[i], acc[2][i]);
            acc[3][i] = fmaf(a, (float)v3[i], acc[3][i]);
        }
    }

    const float inv = (e1 > e0) ? (1.0f / denom) : 0.0f;
    unsigned short* op = agg + (size_t)r * 256 + h * 32;
#pragma unroll
    for (int j = 0; j < 4; j++) {
        f16x8 ov;
#pragma unroll
        for (int i = 0; i < 8; i++) ov[i] = (_Float16)fmaxf(acc[j][i] * inv, 0.0f);
        *(f16x8*)(op + j * 8) = ov;
    }
}

// ---------------------------------------------------------------------------
extern "C" void kernel_launch(void* const* d_in, const int* in_sizes, int n_in,
                              void* d_out, int out_size, void* d_ws, size_t ws_size,
                              hipStream_t stream) {
    const float* x  = (const float*)d_in[0];
    const int* eidx = (const int*)d_in[1];
    const float* Wk = (const float*)d_in[2];
    const float* bk = (const float*)d_in[3];
    const float* Wq = (const float*)d_in[4];
    const float* bq = (const float*)d_in[5];
    const float* Wv = (const float*)d_in[6];
    const float* bv = (const float*)d_in[7];
    const float* Wa = (const float*)d_in[8];
    const float* ba = (const float*)d_in[9];
    const float* Wf = (const float*)d_in[10];
    const float* bf_ = (const float*)d_in[11];
    float* out = (float*)d_out;

    const int N = in_sizes[0] / D_EMB;   // 50000
    const int M = in_sizes[1] / 2;       // 400000
    const int* recv = eidx;
    const int* send = eidx + M;

    // ---- workspace layout ----
    unsigned short* x_h = (unsigned short*)d_ws;             // N*512 (live until Wf resid)
    unsigned short* kqv = x_h + (size_t)N * 512;             // N*768
    unsigned short* agg = kqv + (size_t)N * FKQV;            // N*256
    unsigned short* Wkqv_h = agg + (size_t)N * 256;          // 768*512
    unsigned short* Wat_h  = Wkqv_h + 768 * 512;             // 512*256
    unsigned short* Wft_h  = Wat_h + 512 * 256;              // 512*512
    float* b_kqv = (float*)(Wft_h + 512 * 512);              // 768
    int* rowptr = (int*)(b_kqv + 768);                       // N+1
    int* cursor = rowptr + (N + 1);                          // N
    int* bsum   = cursor + N;                                // 64
    int* ssend  = bsum + 64;                                 // M
    unsigned short* h1 = kqv;   // alias: kqv dead after attention

    const int nb = (N + 1023) / 1024;  // 49

    // ---- CSR build ----
    hipMemsetAsync(cursor, 0, (size_t)N * sizeof(int), stream);
    count_deg_kernel<<<(M + 255) / 256, 256, 0, stream>>>(recv, cursor, M);
    scan_block_kernel<<<nb, 1024, 0, stream>>>(cursor, rowptr, bsum, N);
    scan_carry_kernel<<<1, 64, 0, stream>>>(bsum, rowptr, nb);
    add_carry_kernel<<<(N + 255) / 256, 256, 0, stream>>>(rowptr, bsum, N);
    hipMemsetAsync(cursor, 0, (size_t)N * sizeof(int), stream);
    scatter_kernel<<<(M + 255) / 256, 256, 0, stream>>>(recv, send, rowptr, cursor, ssend, M);

    // ---- input cvt + weight prep ----
    cvt_x_kernel<<<((N * 512 / 8) + 255) / 256, 256, 0, stream>>>(x, x_h, N * 512 / 8);
    {
        dim3 b(32, 8);
        transpose_cvt_kernel<<<dim3(16, 8), b, 0, stream>>>(Wk, Wkqv_h, 512, 256, 0,   512);
        transpose_cvt_kernel<<<dim3(16, 8), b, 0, stream>>>(Wq, Wkqv_h, 512, 256, 256, 512);
        transpose_cvt_kernel<<<dim3(16, 8), b, 0, stream>>>(Wv, Wkqv_h, 512, 256, 512, 512);
        transpose_cvt_kernel<<<dim3(8, 16), b, 0, stream>>>(Wa, Wat_h, 256, 512, 0, 256);
        transpose_cvt_kernel<<<dim3(16, 16), b, 0, stream>>>(Wf, Wft_h, 512, 512, 0, 512);
    }
    bias_pack_kernel<<<3, 256, 0, stream>>>(bk, bq, bv, b_kqv);

    const int gy = (N + 127) / 128;  // 391

    // ---- KQV = x @ [Wk|Wq|Wv] + b -> fp16 [N][768] ----
    gemm_f16_kernel<0, false><<<dim3(FKQV / 128, gy), 256, 0, stream>>>(
        x_h, Wkqv_h, b_kqv, nullptr, kqv, N, 512, FKQV);

    // ---- fused attention gather -> agg fp16 [N][256] ----
    attn_fused_kernel<<<(N * HEADS + 255) / 256, 256, 0, stream>>>(kqv, rowptr, ssend, agg, N);

    // ---- h1 = relu(agg @ Wa + ba) -> fp16 [N][512] (into kqv region) ----
    gemm_f16_kernel<0, true><<<dim3(4, gy), 256, 0, stream>>>(
        agg, Wat_h, ba, nullptr, h1, N, 256, 512);

    // ---- out = x_h + relu(h1 @ Wf + bf) -> fp32 ----
    gemm_f16_kernel<2, true><<<dim3(4, gy), 256, 0, stream>>>(
        h1, Wft_h, bf_, x_h, out, N, 512, 512);
}